// Round 1
// baseline (418.862 us; speedup 1.0000x reference)
//
#include <hip/hip_runtime.h>

// Problem constants (from setup_inputs):
//   images=8, patches=3600 (=60*60), hor_f=64, ver_f=25 (=5*5), pixels 64x64, k=5
#define KW     5
#define OH     60      // pixels - k + 1
#define PIX    64
#define NIMG   8
#define HF     64
#define VF     25
#define NPATCH 3600

// img layout: [n=im*64+h][i][j], n-major, 512*64*64 floats = 8.4 MB (in d_ws)

__global__ void fold_kernel(const float* __restrict__ x, float* __restrict__ img) {
    unsigned tid = blockIdx.x * blockDim.x + threadIdx.x;   // 512*64*64 = 2097152
    unsigned j = tid & 63u;
    unsigned i = (tid >> 6) & 63u;
    unsigned n = tid >> 12;          // 0..511
    unsigned h = n & 63u;
    unsigned im = n >> 6;

    int ii = (int)i, jj = (int)j;
    int di_lo = ii > (OH - 1) ? ii - (OH - 1) : 0;
    int di_hi = ii < (KW - 1) ? ii : (KW - 1);
    int dj_lo = jj > (OH - 1) ? jj - (OH - 1) : 0;
    int dj_hi = jj < (KW - 1) ? jj : (KW - 1);

    float sum = 0.f;
    for (int di = di_lo; di <= di_hi; ++di) {
        int pi = ii - di;
        for (int dj = dj_lo; dj <= dj_hi; ++dj) {
            int pj = jj - dj;
            unsigned p = (unsigned)(pi * OH + pj);
            unsigned v = (unsigned)(di * KW + dj);
            // x[im][p][h][v]
            unsigned idx = ((im * NPATCH + p) * HF + h) * VF + v;
            sum += x[idx];
        }
    }
    float cnt = (float)((di_hi - di_lo + 1) * (dj_hi - dj_lo + 1));
    img[tid] = sum / cnt;
}

__global__ void unfold_kernel(const float* __restrict__ img, float4* __restrict__ out) {
    unsigned t = blockIdx.x * blockDim.x + threadIdx.x;   // 11,520,000 threads
    unsigned f0 = t * 4u;                                  // flat out index, < 2^31
    float4 r;
    float* rp = &r.x;
#pragma unroll
    for (int e = 0; e < 4; ++e) {
        unsigned f = f0 + (unsigned)e;
        unsigned v  = f % 25u;
        unsigned q  = f / 25u;
        unsigned h  = q & 63u;
        unsigned q2 = q >> 6;
        unsigned p  = q2 % 3600u;
        unsigned im = q2 / 3600u;
        unsigned pi = p / 60u, pj = p % 60u;
        unsigned di = v / 5u,  dj = v % 5u;
        // img[(im*64+h)][pi+di][pj+dj]
        unsigned idx = (((im << 6) + h) << 12) + ((pi + di) << 6) + (pj + dj);
        rp[e] = img[idx];
    }
    out[t] = r;
}

extern "C" void kernel_launch(void* const* d_in, const int* in_sizes, int n_in,
                              void* d_out, int out_size, void* d_ws, size_t ws_size,
                              hipStream_t stream) {
    const float* x = (const float*)d_in[0];
    float* img = (float*)d_ws;            // 512*64*64*4 = 8,388,608 bytes
    float* out = (float*)d_out;

    const int threads1 = 512 * 64 * 64;   // 2,097,152
    fold_kernel<<<threads1 / 256, 256, 0, stream>>>(x, img);

    const int threads2 = (NIMG * NPATCH * HF * VF) / 4;  // 11,520,000
    unfold_kernel<<<threads2 / 256, 256, 0, stream>>>(img, (float4*)out);
    (void)out_size; (void)ws_size; (void)in_sizes; (void)n_in;
}

// Round 2
// 223.758 us; speedup vs baseline: 1.8719x; 1.8719x over previous
//
#include <hip/hip_runtime.h>

// Problem constants: images=8, patches=3600(=60*60), hor_f=64, ver_f=25(=5*5), 64x64 px, k=5
#define KW     5
#define OH     60
#define NIMG   8
#define HF     64
#define VF     25
#define NPATCH 3600
#define CDIM   (HF * VF)          // 1600
#define IMSZ   ((size_t)NPATCH * CDIM)  // 5,760,000 floats per image

// ---------------- transpose: X[p][c] (3600x1600) -> XT[c][p] (1600x3600), per im ----
__global__ void transpose_kernel(const float* __restrict__ x, float* __restrict__ xt) {
    __shared__ float tile[64][65];
    int im = blockIdx.z;
    int c0 = blockIdx.x * 64;     // 25 tiles, exact
    int p0 = blockIdx.y * 64;     // 57 tiles, last partial (3600 % 64 == 16)
    const float* X  = x  + (size_t)im * IMSZ;
    float*       XT = xt + (size_t)im * IMSZ;
    int t = threadIdx.x;          // 0..255

    // load: float4 along c (coalesced rows)
    {
        int cx = (t & 15) * 4;
        int rr = t >> 4;          // 0..15
#pragma unroll
        for (int k = 0; k < 4; ++k) {
            int r = rr + k * 16;
            int p = p0 + r;
            if (p < NPATCH) {
                float4 v = *reinterpret_cast<const float4*>(&X[(size_t)p * CDIM + c0 + cx]);
                tile[r][cx]     = v.x;
                tile[r][cx + 1] = v.y;
                tile[r][cx + 2] = v.z;
                tile[r][cx + 3] = v.w;
            }
        }
    }
    __syncthreads();
    // store: float4 along p (coalesced rows of XT)
    {
        int px  = (t & 15) * 4;
        int cr0 = t >> 4;         // 0..15
        int p   = p0 + px;
        if (p + 3 < NPATCH) {
#pragma unroll
            for (int k = 0; k < 4; ++k) {
                int cr = cr0 + k * 16;
                float4 v;
                v.x = tile[px][cr];
                v.y = tile[px + 1][cr];
                v.z = tile[px + 2][cr];
                v.w = tile[px + 3][cr];
                *reinterpret_cast<float4*>(&XT[(size_t)(c0 + cr) * NPATCH + p]) = v;
            }
        }
    }
}

// ---------------- fold: xt[(im,h,v)][p] -> img[(im,h)][i][j], divided by overlap count --
__global__ void fold_kernel(const float* __restrict__ xt, float* __restrict__ img) {
    unsigned tid = blockIdx.x * blockDim.x + threadIdx.x;  // nch*4096 threads
    unsigned j = tid & 63u;
    unsigned i = (tid >> 6) & 63u;
    unsigned n = tid >> 12;        // local channel: iml*64 + h
    unsigned h = n & 63u;
    unsigned iml = n >> 6;

    const float* base = xt + (size_t)iml * IMSZ + (size_t)h * VF * NPATCH;

    int ii = (int)i, jj = (int)j;
    int di_lo = ii > (OH - 1) ? ii - (OH - 1) : 0;
    int di_hi = ii < (KW - 1) ? ii : (KW - 1);
    int dj_lo = jj > (OH - 1) ? jj - (OH - 1) : 0;
    int dj_hi = jj < (KW - 1) ? jj : (KW - 1);

    float sum = 0.f;
    for (int di = di_lo; di <= di_hi; ++di) {
        int pi = ii - di;
        for (int dj = dj_lo; dj <= dj_hi; ++dj) {
            int pj = jj - dj;
            int p = pi * OH + pj;
            int v = di * KW + dj;
            sum += base[(size_t)v * NPATCH + p];   // coalesced: adjacent j -> adjacent p
        }
    }
    float cnt = (float)((di_hi - di_lo + 1) * (dj_hi - dj_lo + 1));
    img[tid] = sum / cnt;
}

// ---------------- unfold: img -> out[im][p][h][v], coalesced float4 writes -------------
__global__ void unfold_kernel(const float* __restrict__ img, float4* __restrict__ out) {
    unsigned t = blockIdx.x * blockDim.x + threadIdx.x;   // 11,520,000 threads
    unsigned f0 = t * 4u;
    float4 r;
    float* rp = &r.x;
#pragma unroll
    for (int e = 0; e < 4; ++e) {
        unsigned f = f0 + (unsigned)e;
        unsigned v  = f % 25u;
        unsigned q  = f / 25u;
        unsigned h  = q & 63u;
        unsigned q2 = q >> 6;
        unsigned p  = q2 % 3600u;
        unsigned im = q2 / 3600u;
        unsigned pi = p / 60u, pj = p % 60u;
        unsigned di = v / 5u,  dj = v % 5u;
        unsigned idx = (((im << 6) + h) << 12) + ((pi + di) << 6) + (pj + dj);
        rp[e] = img[idx];
    }
    out[t] = r;
}

extern "C" void kernel_launch(void* const* d_in, const int* in_sizes, int n_in,
                              void* d_out, int out_size, void* d_ws, size_t ws_size,
                              hipStream_t stream) {
    const float* x = (const float*)d_in[0];
    float* out = (float*)d_out;

    const size_t img_floats = (size_t)NIMG * HF * 64 * 64;      // 2,097,152
    const size_t full_need  = ((size_t)NIMG * IMSZ + img_floats) * 4;  // ~192.7 MB

    if (ws_size >= full_need) {
        float* xt  = (float*)d_ws;                   // 8 * IMSZ floats
        float* img = xt + (size_t)NIMG * IMSZ;
        transpose_kernel<<<dim3(25, 57, NIMG), 256, 0, stream>>>(x, xt);
        fold_kernel<<<(NIMG * 64 * 4096) / 256, 256, 0, stream>>>(xt, img);
        unfold_kernel<<<(NIMG * NPATCH * HF * VF) / 4 / 256, 256, 0, stream>>>(img, (float4*)out);
    } else {
        // per-image fallback: xt for one image + full img accumulator
        float* xt  = (float*)d_ws;                   // IMSZ floats (23 MB)
        float* img = xt + IMSZ;                      // 2M floats (8.4 MB)
        for (int im = 0; im < NIMG; ++im) {
            transpose_kernel<<<dim3(25, 57, 1), 256, 0, stream>>>(x + (size_t)im * IMSZ, xt);
            fold_kernel<<<(64 * 4096) / 256, 256, 0, stream>>>(xt, img + (size_t)im * 64 * 4096);
        }
        unfold_kernel<<<(NIMG * NPATCH * HF * VF) / 4 / 256, 256, 0, stream>>>(img, (float4*)out);
    }
    (void)out_size; (void)in_sizes; (void)n_in;
}

// Round 3
// 213.205 us; speedup vs baseline: 1.9646x; 1.0495x over previous
//
#include <hip/hip_runtime.h>

// images=8, patches=3600(=60*60), hor_f=64, ver_f=25(=5*5), 64x64 px, k=5
#define KW     5
#define OH     60
#define NIMG   8
#define HF     64
#define VF     25
#define NPATCH 3600
#define CDIM   1600                      // HF*VF
#define IMSZ   ((size_t)NPATCH * CDIM)
#define HG     16                        // h channels per block
#define NHG    (HF / HG)                 // 4
#define NP     12                        // patches staged per chunk
#define NCHUNK (OH / NP)                 // 5

// img (d_ws): [n=im*64+h][i][j] = 512*64*64 floats = 8.4 MB

__global__ __launch_bounds__(256) void zero_kernel(float4* __restrict__ img) {
    unsigned t = blockIdx.x * 256u + threadIdx.x;
    img[t] = float4{0.f, 0.f, 0.f, 0.f};
}

__global__ __launch_bounds__(256) void fold_fused(const float* __restrict__ x,
                                                  float* __restrict__ img) {
    __shared__ float lds[NP * 400];      // 12 patches x (16 h x 25 v) = 18.75 KB
    unsigned b  = blockIdx.x;            // b = pi + OH*(hg + NHG*im)
    unsigned pi = b % OH;
    unsigned hg = (b / OH) % NHG;
    unsigned im = b / (OH * NHG);
    unsigned t  = threadIdx.x;
    unsigned h0 = hg * HG;
    unsigned j  = t & 63u;

    // source: x[im][pi*60 + pj][h0..h0+15][0..24]  (400 contiguous floats per patch)
    const float* src = x + ((size_t)im * NPATCH + (size_t)pi * OH) * CDIM + h0 * VF;

    float acc[20];
#pragma unroll
    for (int k = 0; k < 20; ++k) acc[k] = 0.f;

    for (int c = 0; c < NCHUNK; ++c) {
        int p0 = c * NP;
        __syncthreads();                 // protect lds from previous iteration's readers
        for (unsigned u = t; u < NP * 100u; u += 256u) {
            unsigned pp = u / 100u, c4 = u % 100u;
            float4 v = *reinterpret_cast<const float4*>(src + (size_t)(p0 + pp) * CDIM + c4 * 4u);
            *reinterpret_cast<float4*>(&lds[pp * 400u + c4 * 4u]) = v;
        }
        __syncthreads();
        // slot s = t + 256k -> di = s>>10, hh = (s>>6)&15, col j = s&63 (fixed per thread)
        int djlo = max(0, (int)j - (p0 + NP - 1));
        int djhi = min(4, (int)j - p0);
        if (djlo <= djhi) {
#pragma unroll
            for (int k = 0; k < 20; ++k) {
                unsigned s  = t + 256u * k;
                unsigned hh = (s >> 6) & 15u;
                unsigned di = s >> 10;
                unsigned base = hh * VF + di * KW;
                for (int dj = djlo; dj <= djhi; ++dj) {
                    acc[k] += lds[(unsigned)((int)j - dj - p0) * 400u + base + (unsigned)dj];
                }
            }
        }
    }

#pragma unroll
    for (int k = 0; k < 20; ++k) {
        unsigned s  = t + 256u * k;
        unsigned hh = (s >> 6) & 15u;
        unsigned di = s >> 10;
        unsigned n  = (im << 6) + h0 + hh;
        unsigned i  = pi + di;
        atomicAdd(&img[(n << 12) + (i << 6) + j], acc[k]);
    }
}

// unfold + divide-by-count: out[im][p][h][v] = img[im*64+h][pi+di][pj+dj] / cnt
__global__ __launch_bounds__(256) void unfold_kernel(const float* __restrict__ img,
                                                     float4* __restrict__ out) {
    unsigned t = blockIdx.x * 256u + threadIdx.x;   // 11,520,000 threads
    unsigned f0 = t * 4u;
    float4 r;
    float* rp = &r.x;
#pragma unroll
    for (int e = 0; e < 4; ++e) {
        unsigned f  = f0 + (unsigned)e;
        unsigned v  = f % 25u;
        unsigned q  = f / 25u;
        unsigned h  = q & 63u;
        unsigned q2 = q >> 6;
        unsigned p  = q2 % 3600u;
        unsigned im = q2 / 3600u;
        unsigned pi = p / 60u, pj = p % 60u;
        unsigned di = v / 5u,  dj = v % 5u;
        unsigned i = pi + di, j = pj + dj;
        unsigned idx = (((im << 6) + h) << 12) + (i << 6) + j;
        float ci = (float)min(min(i + 1u, 64u - i), 5u);
        float cj = (float)min(min(j + 1u, 64u - j), 5u);
        rp[e] = img[idx] / (ci * cj);
    }
    out[t] = r;
}

extern "C" void kernel_launch(void* const* d_in, const int* in_sizes, int n_in,
                              void* d_out, int out_size, void* d_ws, size_t ws_size,
                              hipStream_t stream) {
    const float* x = (const float*)d_in[0];
    float* img = (float*)d_ws;                      // 2,097,152 floats = 8.4 MB
    float* out = (float*)d_out;

    zero_kernel<<<2048, 256, 0, stream>>>((float4*)img);
    fold_fused<<<NIMG * NHG * OH, 256, 0, stream>>>(x, img);   // 1920 blocks
    unfold_kernel<<<(NIMG * NPATCH * HF * VF) / 4 / 256, 256, 0, stream>>>(img, (float4*)out);

    (void)out_size; (void)ws_size; (void)in_sizes; (void)n_in;
}